// Round 7
// baseline (214.611 us; speedup 1.0000x reference)
//
#include <hip/hip_runtime.h>
#include <math.h>

// Problem constants (HeadAttention_738734374917)
#define Bn  8
#define Nn  2048
#define Dn  1024
#define DHn 64
#define PAD 72   // LDS row pitch (shorts)

typedef __attribute__((ext_vector_type(8))) short bf16x8;  // 8 bf16 = 4 VGPRs
typedef __attribute__((ext_vector_type(4))) float f32x4;

static __device__ inline short f2bf(float f) {
    unsigned u = __builtin_bit_cast(unsigned, f);
    u += 0x7FFFu + ((u >> 16) & 1u);     // round-to-nearest-even
    return (short)(u >> 16);
}
static __device__ inline bf16x8 pack8(float4 a, float4 b) {
    bf16x8 v;
    v[0] = f2bf(a.x); v[1] = f2bf(a.y); v[2] = f2bf(a.z); v[3] = f2bf(a.w);
    v[4] = f2bf(b.x); v[5] = f2bf(b.y); v[6] = f2bf(b.z); v[7] = f2bf(b.w);
    return v;
}

// ---------------------------------------------------------------------------
// Wt in B-FRAG-MAJOR order: Wtf[nt 0..11][kt 0..15][half 0..1][lane 0..63][e 0..7]
// frag (nt,kt,half): lane(quad*16+c) holds W[k=kt*64+half*32+quad*8+e][n=nt*16+c].
// Makes qkv's B-frag loads lane-contiguous (coalesced 1 KB per wave-load).
// ---------------------------------------------------------------------------
__global__ __launch_bounds__(128) void wt_kernel(
    const float* __restrict__ Wq, const float* __restrict__ Wk,
    const float* __restrict__ Wv, short* __restrict__ Wtf)
{
    const int nt = blockIdx.x / 16, kt = blockIdx.x % 16;
    const int t = threadIdx.x;
    const int half = t >> 6, l = t & 63;
    const int c = l & 15, quad = l >> 4;
    const int mat = nt >> 2, cm = (nt & 3) * 16 + c;
    const float* Wm = (mat == 0) ? Wq : (mat == 1 ? Wk : Wv);
    short* o = &Wtf[((((size_t)nt * 16 + kt) * 2 + half) * 64 + l) * 8];
#pragma unroll
    for (int e = 0; e < 8; ++e) {
        const int k = kt * 64 + half * 32 + quad * 8 + e;
        o[e] = f2bf(Wm[(size_t)k * DHn + cm]);
    }
}

// ---------------------------------------------------------------------------
// K1: QKV projection, bf16 MFMA, BARRIER-FREE k-loop.
// Grid 1024 x 128 thr (8 waves/CU).  Block = 16 rows of x; wave w owns
// k-half [w*512, w*512+512) = 8 BK=64 iters, wave-private LDS staging of x
// (in-order DS, no __syncthreads in loop), frag-major Wtf B-loads, 12 accs.
// End: one barrier, 2-way k-reduce through LDS, split epilogue.
// Outputs: Qb[i][d], Kb[j][d]*0.125, Vt[b][d][j] — all bf16.
// ---------------------------------------------------------------------------
__global__ __launch_bounds__(128) void qkv_kernel(
    const float* __restrict__ x, const short* __restrict__ Wtf,
    const float* __restrict__ bq, const float* __restrict__ bk,
    const float* __restrict__ bv,
    short* __restrict__ Qb, short* __restrict__ Kb, short* __restrict__ Vt)
{
    __shared__ __attribute__((aligned(16))) short xs[2][2][16][PAD];
    __shared__ f32x4 red[2][6 * 64];   // cross-k partials: [src wave][nt-slot*64+lane]

    const int t = threadIdx.x;
    const int w = t >> 6, l = t & 63;
    const int c = l & 15, quad = l >> 4;
    const int ibase = blockIdx.x * 16;
    const int srow = l >> 2, scol = (l & 3) * 16;   // staging: lane -> row, 16-float chunk

    const float* xbase = &x[(size_t)(ibase + srow) * Dn + w * 512 + scol];

    // stage kt=0 into buf 0
    {
        const float4* p = (const float4*)xbase;
        *(bf16x8*)&xs[w][0][srow][scol]     = pack8(p[0], p[1]);
        *(bf16x8*)&xs[w][0][srow][scol + 8] = pack8(p[2], p[3]);
    }

    f32x4 acc[12];
#pragma unroll
    for (int nt = 0; nt < 12; ++nt) acc[nt] = (f32x4){0.f, 0.f, 0.f, 0.f};

    for (int kt = 0; kt < 8; ++kt) {
        const int cur = kt & 1;
        // prefetch x for kt+1 (issue before compute)
        float4 p0, p1, p2, p3;
        if (kt < 7) {
            const float4* p = (const float4*)(xbase + (kt + 1) * 64);
            p0 = p[0]; p1 = p[1]; p2 = p[2]; p3 = p[3];
        }
        const int ktg = w * 8 + kt;   // global kt index into Wtf
#pragma unroll
        for (int h = 0; h < 2; ++h) {
            const bf16x8 af = *(const bf16x8*)&xs[w][cur][c][h * 32 + quad * 8];
            const short* wrow = &Wtf[(((size_t)ktg * 2 + h) * 64 + l) * 8];
#pragma unroll
            for (int nt = 0; nt < 12; ++nt) {
                const bf16x8 bf = *(const bf16x8*)&wrow[(size_t)nt * 16 * 2 * 64 * 8];
                acc[nt] = __builtin_amdgcn_mfma_f32_16x16x32_bf16(af, bf, acc[nt], 0, 0, 0);
            }
        }
        // stage kt+1 (wave-private: in-order DS, no barrier)
        if (kt < 7) {
            *(bf16x8*)&xs[w][1 - cur][srow][scol]     = pack8(p0, p1);
            *(bf16x8*)&xs[w][1 - cur][srow][scol + 8] = pack8(p2, p3);
        }
    }

    // cross-k reduce: wave 0 epilogues nt 0..5, wave 1 epilogues nt 6..11
#pragma unroll
    for (int q = 0; q < 6; ++q) {
        const int nt = (w == 0) ? (6 + q) : q;   // give away the other half
        red[w][q * 64 + l] = acc[nt];
    }
    __syncthreads();
#pragma unroll
    for (int q = 0; q < 6; ++q) {
        const int nt = w * 6 + q;
        const f32x4 o = red[1 - w][q * 64 + l];
        acc[nt][0] += o[0]; acc[nt][1] += o[1]; acc[nt][2] += o[2]; acc[nt][3] += o[3];
    }

    const int b = ibase >> 11;
#pragma unroll
    for (int q = 0; q < 6; ++q) {
        const int nt = w * 6 + q;
        const int mat = nt >> 2, cm = (nt & 3) * 16 + c;
        const float bias = (mat == 0 ? bq : (mat == 1 ? bk : bv))[cm];
        if (mat == 2) {
            const int i = (ibase & (Nn - 1)) + quad * 4;
            ushort4 o;
            o.x = (unsigned short)f2bf(acc[nt][0] + bias);
            o.y = (unsigned short)f2bf(acc[nt][1] + bias);
            o.z = (unsigned short)f2bf(acc[nt][2] + bias);
            o.w = (unsigned short)f2bf(acc[nt][3] + bias);
            *(ushort4*)&Vt[((size_t)b * DHn + cm) * Nn + i] = o;
        } else {
            const float s = (mat == 1) ? 0.125f : 1.0f;
            short* Out = (mat == 0) ? Qb : Kb;
#pragma unroll
            for (int r = 0; r < 4; ++r)
                Out[(size_t)(ibase + quad * 4 + r) * DHn + cm] =
                    f2bf((acc[nt][r] + bias) * s);
        }
    }
}

// ---------------------------------------------------------------------------
// K2: l_part[s][b][j] = sum_{i in split s} exp(Q_i . K'_j).
// Grid (b, j-tile 64, i-split 4) = 1024 x 256.  K-frags register-resident;
// Q staged WAVE-PRIVATE (zero barriers in loop).  Plain stores.
// ---------------------------------------------------------------------------
__global__ __launch_bounds__(256) void colsum_kernel(
    const short* __restrict__ Qb, const short* __restrict__ Kb,
    float* __restrict__ lpart)
{
    __shared__ __attribute__((aligned(16))) short Qw[4][2][16][PAD];
    __shared__ float red[16][64];

    const int t = threadIdx.x;
    const int w = t >> 6, l = t & 63;
    const int c = l & 15, quad = l >> 4;
    const int bid = blockIdx.x;
    const int b = bid >> 7, rem = bid & 127, jt = rem >> 2, s = rem & 3;
    const int jbase = jt * 64;
    const int srow = l >> 2, scol = (l & 3) * 16;

    bf16x8 kb[4][2];
#pragma unroll
    for (int nt = 0; nt < 4; ++nt)
#pragma unroll
        for (int kk = 0; kk < 2; ++kk)
            kb[nt][kk] = *(const bf16x8*)&Kb[((size_t)b * Nn + jbase + nt * 16 + c) * DHn
                                             + kk * 32 + quad * 8];

    // wave w handles i-chunks (ch*4 + w)*16 within split s
    const short* qbase = &Qb[((size_t)b * Nn + s * 512 + w * 16 + srow) * DHn + scol];

    // stage ch=0 into buf 0 (wave-private)
    *(bf16x8*)&Qw[w][0][srow][scol]     = *(const bf16x8*)qbase;
    *(bf16x8*)&Qw[w][0][srow][scol + 8] = *(const bf16x8*)(qbase + 8);

    float lsum[4] = {0.f, 0.f, 0.f, 0.f};

    for (int ch = 0; ch < 8; ++ch) {
        const int cur = ch & 1;
        bf16x8 p0, p1;
        if (ch < 7) {
            const short* pq = qbase + (size_t)(ch + 1) * 64 * DHn;
            p0 = *(const bf16x8*)pq; p1 = *(const bf16x8*)(pq + 8);
        }
        const bf16x8 aq0 = *(const bf16x8*)&Qw[w][cur][c][quad * 8];
        const bf16x8 aq1 = *(const bf16x8*)&Qw[w][cur][c][32 + quad * 8];
#pragma unroll
        for (int nt = 0; nt < 4; ++nt) {
            f32x4 sv = (f32x4){0.f, 0.f, 0.f, 0.f};
            sv = __builtin_amdgcn_mfma_f32_16x16x32_bf16(aq0, kb[nt][0], sv, 0, 0, 0);
            sv = __builtin_amdgcn_mfma_f32_16x16x32_bf16(aq1, kb[nt][1], sv, 0, 0, 0);
            lsum[nt] += __expf(sv[0]) + __expf(sv[1]) + __expf(sv[2]) + __expf(sv[3]);
        }
        if (ch < 7) {
            *(bf16x8*)&Qw[w][1 - cur][srow][scol]     = p0;
            *(bf16x8*)&Qw[w][1 - cur][srow][scol + 8] = p1;
        }
        // no barrier: Qw[w] is wave-private, DS ops are in-order per wave
    }

#pragma unroll
    for (int nt = 0; nt < 4; ++nt) red[w * 4 + quad][nt * 16 + c] = lsum[nt];
    __syncthreads();
    if (t < 64) {
        float sum = 0.f;
#pragma unroll
        for (int r = 0; r < 16; ++r) sum += red[r][t];
        lpart[((size_t)s * Bn + b) * Nn + jbase + t] = sum;   // plain store
    }
}

// ---------------------------------------------------------------------------
// K3: outp[s][i,:] = sum_{j in s} (exp(Q_i.K'_j)/l_j) V[j,:].
// Grid = (b, i-tile 64, j-split 4) = 1024.  K/V double-buffered LDS staging
// (ONE barrier per tile); rl = 1/(sum of 4 l_parts) folded into P at exp;
// Ps wave-private C->A bounce; plain stores to per-split partials.
// ---------------------------------------------------------------------------
__global__ __launch_bounds__(256) void attnout_kernel(
    const short* __restrict__ Qb, const short* __restrict__ Kb,
    const short* __restrict__ Vt, const float* __restrict__ lpart,
    float* __restrict__ outp)
{
    __shared__ __attribute__((aligned(16))) short Ks[2][64][PAD];
    __shared__ __attribute__((aligned(16))) short Vs[2][64][PAD];
    __shared__ __attribute__((aligned(16))) short Ps[4][16][PAD];  // wave-private
    __shared__ float rls[2][64];

    const int t = threadIdx.x;
    const int w = t >> 6, lane = t & 63;
    const int c = lane & 15, quad = lane >> 4;
    const int bid = blockIdx.x;
    const int b = bid >> 7, rem = bid & 127, it = rem >> 2, s = rem & 3;
    const int ibase = it * 64;
    const int r0 = t >> 2, cc = (t & 3) * 16;

    const size_t qrow = (size_t)b * Nn + ibase + w * 16 + c;
    const bf16x8 aq0 = *(const bf16x8*)&Qb[qrow * DHn + quad * 8];
    const bf16x8 aq1 = *(const bf16x8*)&Qb[qrow * DHn + 32 + quad * 8];

    const short* kbase = &Kb[((size_t)b * Nn + s * 512 + r0) * DHn + cc];
    const short* vbase = &Vt[((size_t)b * DHn + r0) * Nn + s * 512 + cc];

    // stage tile 0 + rls[0]
    *(bf16x8*)&Ks[0][r0][cc]     = *(const bf16x8*)kbase;
    *(bf16x8*)&Ks[0][r0][cc + 8] = *(const bf16x8*)(kbase + 8);
    *(bf16x8*)&Vs[0][r0][cc]     = *(const bf16x8*)vbase;
    *(bf16x8*)&Vs[0][r0][cc + 8] = *(const bf16x8*)(vbase + 8);
    if (t < 64) {
        const size_t lj = (size_t)b * Nn + s * 512 + t;
        rls[0][t] = 1.0f / (lpart[lj] + lpart[(size_t)Bn * Nn + lj]
                          + lpart[2 * (size_t)Bn * Nn + lj] + lpart[3 * (size_t)Bn * Nn + lj]);
    }

    f32x4 acc[4];
#pragma unroll
    for (int dn = 0; dn < 4; ++dn) acc[dn] = (f32x4){0.f, 0.f, 0.f, 0.f};
    __syncthreads();

    for (int jt2 = 0; jt2 < 8; ++jt2) {
        const int cur = jt2 & 1;
        // prefetch next tile into registers
        bf16x8 pk0, pk1, pv0, pv1; float nrl;
        if (jt2 < 7) {
            const short* pk = kbase + (size_t)(jt2 + 1) * 64 * DHn;
            pk0 = *(const bf16x8*)pk; pk1 = *(const bf16x8*)(pk + 8);
            const short* pv = vbase + (jt2 + 1) * 64;
            pv0 = *(const bf16x8*)pv; pv1 = *(const bf16x8*)(pv + 8);
            if (t < 64) {
                const size_t lj = (size_t)b * Nn + s * 512 + (jt2 + 1) * 64 + t;
                nrl = 1.0f / (lpart[lj] + lpart[(size_t)Bn * Nn + lj]
                            + lpart[2 * (size_t)Bn * Nn + lj] + lpart[3 * (size_t)Bn * Nn + lj]);
            }
        }

        // S = Q.K'^T (16 i x 64 j per wave) -> P = exp(S)*rl -> Ps (A-layout)
#pragma unroll
        for (int nt = 0; nt < 4; ++nt) {
            const bf16x8 kb0 = *(const bf16x8*)&Ks[cur][nt * 16 + c][quad * 8];
            const bf16x8 kb1 = *(const bf16x8*)&Ks[cur][nt * 16 + c][32 + quad * 8];
            f32x4 sv = (f32x4){0.f, 0.f, 0.f, 0.f};
            sv = __builtin_amdgcn_mfma_f32_16x16x32_bf16(aq0, kb0, sv, 0, 0, 0);
            sv = __builtin_amdgcn_mfma_f32_16x16x32_bf16(aq1, kb1, sv, 0, 0, 0);
            const float rl = rls[cur][nt * 16 + c];
#pragma unroll
            for (int r = 0; r < 4; ++r)
                Ps[w][quad * 4 + r][nt * 16 + c] = f2bf(__expf(sv[r]) * rl);
        }
        // wave-private: same-wave DS ops are in-order, no block barrier
        const bf16x8 ap0 = *(const bf16x8*)&Ps[w][c][quad * 8];
        const bf16x8 ap1 = *(const bf16x8*)&Ps[w][c][32 + quad * 8];
#pragma unroll
        for (int dn = 0; dn < 4; ++dn) {
            const bf16x8 vb0 = *(const bf16x8*)&Vs[cur][dn * 16 + c][quad * 8];
            const bf16x8 vb1 = *(const bf16x8*)&Vs[cur][dn * 16 + c][32 + quad * 8];
            acc[dn] = __builtin_amdgcn_mfma_f32_16x16x32_bf16(ap0, vb0, acc[dn], 0, 0, 0);
            acc[dn] = __builtin_amdgcn_mfma_f32_16x16x32_bf16(ap1, vb1, acc[dn], 0, 0, 0);
        }

        if (jt2 < 7) {
            *(bf16x8*)&Ks[1 - cur][r0][cc]     = pk0;
            *(bf16x8*)&Ks[1 - cur][r0][cc + 8] = pk1;
            *(bf16x8*)&Vs[1 - cur][r0][cc]     = pv0;
            *(bf16x8*)&Vs[1 - cur][r0][cc + 8] = pv1;
            if (t < 64) rls[1 - cur][t] = nrl;
        }
        __syncthreads();
    }

    float* op = outp + (size_t)s * (Bn * Nn * DHn) + ((size_t)b * Nn + ibase) * DHn;
#pragma unroll
    for (int dn = 0; dn < 4; ++dn)
#pragma unroll
        for (int r = 0; r < 4; ++r)
            op[(w * 16 + quad * 4 + r) * DHn + dn * 16 + c] = acc[dn][r];
}

// ---------------------------------------------------------------------------
// Reduce the 4 partial buffers into out.
// ---------------------------------------------------------------------------
__global__ __launch_bounds__(256) void outreduce_kernel(
    const float* __restrict__ outp, float* __restrict__ out)
{
    const int id = blockIdx.x * 256 + threadIdx.x;   // 262144 float4
    const float4* p = (const float4*)outp;
    const float4 a = p[id];
    const float4 b = p[id + 262144];
    const float4 c = p[id + 2 * 262144];
    const float4 d = p[id + 3 * 262144];
    float4 r;
    r.x = a.x + b.x + c.x + d.x;
    r.y = a.y + b.y + c.y + d.y;
    r.z = a.z + b.z + c.z + d.z;
    r.w = a.w + b.w + c.w + d.w;
    ((float4*)out)[id] = r;
}

// ---------------------------------------------------------------------------
extern "C" void kernel_launch(void* const* d_in, const int* in_sizes, int n_in,
                              void* d_out, int out_size, void* d_ws, size_t ws_size,
                              hipStream_t stream)
{
    const float* x  = (const float*)d_in[0];
    const float* Wq = (const float*)d_in[1];
    const float* bq = (const float*)d_in[2];
    const float* Wk = (const float*)d_in[3];
    const float* bk = (const float*)d_in[4];
    const float* Wv = (const float*)d_in[5];
    const float* bv = (const float*)d_in[6];
    float* out = (float*)d_out;

    char* ws = (char*)d_ws;
    short* Qb    = (short*)(ws);                                   // 2 MB
    short* Kb    = (short*)(ws + (size_t)(1 << 21));               // 2 MB
    short* Vt    = (short*)(ws + (size_t)(2 << 21));               // 2 MB [b][d][j]
    short* Wtf   = (short*)(ws + (size_t)(3 << 21));               // 384 KB (frag-major)
    float* lpart = (float*)(ws + (size_t)(3 << 21) + (1 << 19));   // 256 KB (4 splits)
    float* outp  = (float*)(ws + (size_t)(7 << 20));               // 16 MB (4 partials)

    wt_kernel<<<dim3(192), dim3(128), 0, stream>>>(Wq, Wk, Wv, Wtf);
    qkv_kernel<<<dim3(1024), dim3(128), 0, stream>>>(x, Wtf, bq, bk, bv, Qb, Kb, Vt);
    colsum_kernel<<<dim3(1024), dim3(256), 0, stream>>>(Qb, Kb, lpart);
    attnout_kernel<<<dim3(1024), dim3(256), 0, stream>>>(Qb, Kb, Vt, lpart, outp);
    outreduce_kernel<<<dim3(1024), dim3(256), 0, stream>>>(outp, out);
}

// Round 8
// 160.345 us; speedup vs baseline: 1.3384x; 1.3384x over previous
//
#include <hip/hip_runtime.h>
#include <math.h>

// Problem constants (HeadAttention_738734374917)
#define Bn  8
#define Nn  2048
#define Dn  1024
#define DHn 64
#define PAD 72   // LDS row pitch (shorts)

typedef __attribute__((ext_vector_type(8))) short bf16x8;  // 8 bf16 = 4 VGPRs
typedef __attribute__((ext_vector_type(4))) float f32x4;

static __device__ inline short f2bf(float f) {
    unsigned u = __builtin_bit_cast(unsigned, f);
    u += 0x7FFFu + ((u >> 16) & 1u);     // round-to-nearest-even
    return (short)(u >> 16);
}
static __device__ inline bf16x8 pack8(float4 a, float4 b) {
    bf16x8 v;
    v[0] = f2bf(a.x); v[1] = f2bf(a.y); v[2] = f2bf(a.z); v[3] = f2bf(a.w);
    v[4] = f2bf(b.x); v[5] = f2bf(b.y); v[6] = f2bf(b.z); v[7] = f2bf(b.w);
    return v;
}

// ---------------------------------------------------------------------------
// Wt in B-FRAG-MAJOR order: Wtf[ntg 0..11][kt 0..15][half 0..1][lane 0..63][e 0..7]
// frag (ntg,kt,half): lane(quad*16+c) holds W[k=kt*64+half*32+quad*8+e][n=ntg*16+c].
// qkv's B-frag loads become lane-contiguous (coalesced 1 KB per wave-load).
// ---------------------------------------------------------------------------
__global__ __launch_bounds__(128) void wt_kernel(
    const float* __restrict__ Wq, const float* __restrict__ Wk,
    const float* __restrict__ Wv, short* __restrict__ Wtf)
{
    const int nt = blockIdx.x / 16, kt = blockIdx.x % 16;
    const int t = threadIdx.x;
    const int half = t >> 6, l = t & 63;
    const int c = l & 15, quad = l >> 4;
    const int mat = nt >> 2, cm = (nt & 3) * 16 + c;
    const float* Wm = (mat == 0) ? Wq : (mat == 1 ? Wk : Wv);
    short* o = &Wtf[((((size_t)nt * 16 + kt) * 2 + half) * 64 + l) * 8];
#pragma unroll
    for (int e = 0; e < 8; ++e) {
        const int k = kt * 64 + half * 32 + quad * 8 + e;
        o[e] = f2bf(Wm[(size_t)k * DHn + cm]);
    }
}

// ---------------------------------------------------------------------------
// K1: QKV projection, bf16 MFMA.  r5 structure (M=32, grid 512, 4 waves,
// dbuf xs, ONE barrier/kt, acc 2x3 = 24 AGPRs — no spill) + frag-major Wtf
// B-loads (coalesced 1 KB wave-loads from L2-resident Wtf).
// Outputs: Qb[i][d], Kb[j][d]*0.125, Vt[b][d][j] — all bf16.
// ---------------------------------------------------------------------------
__global__ __launch_bounds__(256) void qkv_kernel(
    const float* __restrict__ x, const short* __restrict__ Wtf,
    const float* __restrict__ bq, const float* __restrict__ bk,
    const float* __restrict__ bv,
    short* __restrict__ Qb, short* __restrict__ Kb, short* __restrict__ Vt)
{
    __shared__ __attribute__((aligned(16))) short xs[2][32][PAD];

    const int t = threadIdx.x;
    const int w = t >> 6, l = t & 63;
    const int c = l & 15, quad = l >> 4;
    const int ibase = blockIdx.x * 32;
    const int r0 = t >> 3, kc = t & 7;      // staging: row r0 (0..31), 8-elem chunk kc

    const float* xrow = &x[(size_t)(ibase + r0) * Dn + kc * 8];

    // stage kt=0 into buf 0
    {
        const float4 a = ((const float4*)xrow)[0];
        const float4 b = ((const float4*)xrow)[1];
        *(bf16x8*)&xs[0][r0][kc * 8] = pack8(a, b);
    }

    f32x4 acc[2][3];
#pragma unroll
    for (int mt = 0; mt < 2; ++mt)
#pragma unroll
        for (int nt = 0; nt < 3; ++nt) acc[mt][nt] = (f32x4){0.f, 0.f, 0.f, 0.f};

    __syncthreads();

    for (int kt = 0; kt < 16; ++kt) {
        const int cur = kt & 1;
        // prefetch x for kt+1
        float4 pa, pb;
        if (kt < 15) {
            pa = ((const float4*)(xrow + (kt + 1) * 64))[0];
            pb = ((const float4*)(xrow + (kt + 1) * 64))[1];
        }
        // compute from buf cur; B-frags coalesced from frag-major Wtf
#pragma unroll
        for (int h = 0; h < 2; ++h) {
            const bf16x8 af0 = *(const bf16x8*)&xs[cur][c][h * 32 + quad * 8];
            const bf16x8 af1 = *(const bf16x8*)&xs[cur][16 + c][h * 32 + quad * 8];
#pragma unroll
            for (int nt = 0; nt < 3; ++nt) {
                const int ntg = w * 3 + nt;
                const bf16x8 bf = *(const bf16x8*)&Wtf[((((size_t)ntg * 16 + kt) * 2 + h) * 64 + l) * 8];
                acc[0][nt] = __builtin_amdgcn_mfma_f32_16x16x32_bf16(af0, bf, acc[0][nt], 0, 0, 0);
                acc[1][nt] = __builtin_amdgcn_mfma_f32_16x16x32_bf16(af1, bf, acc[1][nt], 0, 0, 0);
            }
        }
        // stage kt+1 into the other buffer
        if (kt < 15) *(bf16x8*)&xs[1 - cur][r0][kc * 8] = pack8(pa, pb);
        __syncthreads();
    }

    // epilogue: bias, K-scale, store (mat uniform per (w,nt))
#pragma unroll
    for (int nt = 0; nt < 3; ++nt) {
        const int col = w * 48 + nt * 16 + c;
        const int mat = col >> 6, cm = col & 63;
        const float bias = (mat == 0 ? bq : (mat == 1 ? bk : bv))[cm];
#pragma unroll
        for (int mt = 0; mt < 2; ++mt) {
            if (mat == 2) {
                const int row = ibase + mt * 16 + quad * 4;
                const int b = row >> 11, i = row & (Nn - 1);
                ushort4 o;
                o.x = (unsigned short)f2bf(acc[mt][nt][0] + bias);
                o.y = (unsigned short)f2bf(acc[mt][nt][1] + bias);
                o.z = (unsigned short)f2bf(acc[mt][nt][2] + bias);
                o.w = (unsigned short)f2bf(acc[mt][nt][3] + bias);
                *(ushort4*)&Vt[((size_t)b * DHn + cm) * Nn + i] = o;
            } else {
                const float s = (mat == 1) ? 0.125f : 1.0f;
                short* Out = (mat == 0) ? Qb : Kb;
#pragma unroll
                for (int r = 0; r < 4; ++r)
                    Out[(size_t)(ibase + mt * 16 + quad * 4 + r) * DHn + cm] =
                        f2bf((acc[mt][nt][r] + bias) * s);
            }
        }
    }
}

// ---------------------------------------------------------------------------
// K2: l_part[s][b][j] = sum_{i in split s} exp(Q_i . K'_j).
// Grid (b, j-tile 64, i-split 4) = 1024 x 256.  K-frags register-resident;
// Q staged WAVE-PRIVATE (zero barriers in loop).  Plain stores.
// ---------------------------------------------------------------------------
__global__ __launch_bounds__(256) void colsum_kernel(
    const short* __restrict__ Qb, const short* __restrict__ Kb,
    float* __restrict__ lpart)
{
    __shared__ __attribute__((aligned(16))) short Qw[4][2][16][PAD];
    __shared__ float red[16][64];

    const int t = threadIdx.x;
    const int w = t >> 6, l = t & 63;
    const int c = l & 15, quad = l >> 4;
    const int bid = blockIdx.x;
    const int b = bid >> 7, rem = bid & 127, jt = rem >> 2, s = rem & 3;
    const int jbase = jt * 64;
    const int srow = l >> 2, scol = (l & 3) * 16;

    bf16x8 kb[4][2];
#pragma unroll
    for (int nt = 0; nt < 4; ++nt)
#pragma unroll
        for (int kk = 0; kk < 2; ++kk)
            kb[nt][kk] = *(const bf16x8*)&Kb[((size_t)b * Nn + jbase + nt * 16 + c) * DHn
                                             + kk * 32 + quad * 8];

    // wave w handles i-chunks (ch*4 + w)*16 within split s
    const short* qbase = &Qb[((size_t)b * Nn + s * 512 + w * 16 + srow) * DHn + scol];

    // stage ch=0 into buf 0 (wave-private)
    *(bf16x8*)&Qw[w][0][srow][scol]     = *(const bf16x8*)qbase;
    *(bf16x8*)&Qw[w][0][srow][scol + 8] = *(const bf16x8*)(qbase + 8);

    float lsum[4] = {0.f, 0.f, 0.f, 0.f};

    for (int ch = 0; ch < 8; ++ch) {
        const int cur = ch & 1;
        bf16x8 p0, p1;
        if (ch < 7) {
            const short* pq = qbase + (size_t)(ch + 1) * 64 * DHn;
            p0 = *(const bf16x8*)pq; p1 = *(const bf16x8*)(pq + 8);
        }
        const bf16x8 aq0 = *(const bf16x8*)&Qw[w][cur][c][quad * 8];
        const bf16x8 aq1 = *(const bf16x8*)&Qw[w][cur][c][32 + quad * 8];
#pragma unroll
        for (int nt = 0; nt < 4; ++nt) {
            f32x4 sv = (f32x4){0.f, 0.f, 0.f, 0.f};
            sv = __builtin_amdgcn_mfma_f32_16x16x32_bf16(aq0, kb[nt][0], sv, 0, 0, 0);
            sv = __builtin_amdgcn_mfma_f32_16x16x32_bf16(aq1, kb[nt][1], sv, 0, 0, 0);
            lsum[nt] += __expf(sv[0]) + __expf(sv[1]) + __expf(sv[2]) + __expf(sv[3]);
        }
        if (ch < 7) {
            *(bf16x8*)&Qw[w][1 - cur][srow][scol]     = p0;
            *(bf16x8*)&Qw[w][1 - cur][srow][scol + 8] = p1;
        }
        // no barrier: Qw[w] is wave-private, DS ops are in-order per wave
    }

#pragma unroll
    for (int nt = 0; nt < 4; ++nt) red[w * 4 + quad][nt * 16 + c] = lsum[nt];
    __syncthreads();
    if (t < 64) {
        float sum = 0.f;
#pragma unroll
        for (int r = 0; r < 16; ++r) sum += red[r][t];
        lpart[((size_t)s * Bn + b) * Nn + jbase + t] = sum;   // plain store
    }
}

// ---------------------------------------------------------------------------
// K3: outp[s][i,:] = sum_{j in s} (exp(Q_i.K'_j)/l_j) V[j,:].
// Grid = (b, i-tile 64, j-split 4) = 1024.  K/V double-buffered LDS staging
// (ONE barrier per tile); rl = 1/(sum of 4 l_parts) folded into P at exp;
// Ps wave-private C->A bounce; plain stores to per-split partials.
// ---------------------------------------------------------------------------
__global__ __launch_bounds__(256) void attnout_kernel(
    const short* __restrict__ Qb, const short* __restrict__ Kb,
    const short* __restrict__ Vt, const float* __restrict__ lpart,
    float* __restrict__ outp)
{
    __shared__ __attribute__((aligned(16))) short Ks[2][64][PAD];
    __shared__ __attribute__((aligned(16))) short Vs[2][64][PAD];
    __shared__ __attribute__((aligned(16))) short Ps[4][16][PAD];  // wave-private
    __shared__ float rls[2][64];

    const int t = threadIdx.x;
    const int w = t >> 6, lane = t & 63;
    const int c = lane & 15, quad = lane >> 4;
    const int bid = blockIdx.x;
    const int b = bid >> 7, rem = bid & 127, it = rem >> 2, s = rem & 3;
    const int ibase = it * 64;
    const int r0 = t >> 2, cc = (t & 3) * 16;

    const size_t qrow = (size_t)b * Nn + ibase + w * 16 + c;
    const bf16x8 aq0 = *(const bf16x8*)&Qb[qrow * DHn + quad * 8];
    const bf16x8 aq1 = *(const bf16x8*)&Qb[qrow * DHn + 32 + quad * 8];

    const short* kbase = &Kb[((size_t)b * Nn + s * 512 + r0) * DHn + cc];
    const short* vbase = &Vt[((size_t)b * DHn + r0) * Nn + s * 512 + cc];

    // stage tile 0 + rls[0]
    *(bf16x8*)&Ks[0][r0][cc]     = *(const bf16x8*)kbase;
    *(bf16x8*)&Ks[0][r0][cc + 8] = *(const bf16x8*)(kbase + 8);
    *(bf16x8*)&Vs[0][r0][cc]     = *(const bf16x8*)vbase;
    *(bf16x8*)&Vs[0][r0][cc + 8] = *(const bf16x8*)(vbase + 8);
    if (t < 64) {
        const size_t lj = (size_t)b * Nn + s * 512 + t;
        rls[0][t] = 1.0f / (lpart[lj] + lpart[(size_t)Bn * Nn + lj]
                          + lpart[2 * (size_t)Bn * Nn + lj] + lpart[3 * (size_t)Bn * Nn + lj]);
    }

    f32x4 acc[4];
#pragma unroll
    for (int dn = 0; dn < 4; ++dn) acc[dn] = (f32x4){0.f, 0.f, 0.f, 0.f};
    __syncthreads();

    for (int jt2 = 0; jt2 < 8; ++jt2) {
        const int cur = jt2 & 1;
        // prefetch next tile into registers
        bf16x8 pk0, pk1, pv0, pv1; float nrl;
        if (jt2 < 7) {
            const short* pk = kbase + (size_t)(jt2 + 1) * 64 * DHn;
            pk0 = *(const bf16x8*)pk; pk1 = *(const bf16x8*)(pk + 8);
            const short* pv = vbase + (jt2 + 1) * 64;
            pv0 = *(const bf16x8*)pv; pv1 = *(const bf16x8*)(pv + 8);
            if (t < 64) {
                const size_t lj = (size_t)b * Nn + s * 512 + (jt2 + 1) * 64 + t;
                nrl = 1.0f / (lpart[lj] + lpart[(size_t)Bn * Nn + lj]
                            + lpart[2 * (size_t)Bn * Nn + lj] + lpart[3 * (size_t)Bn * Nn + lj]);
            }
        }

        // S = Q.K'^T (16 i x 64 j per wave) -> P = exp(S)*rl -> Ps (A-layout)
#pragma unroll
        for (int nt = 0; nt < 4; ++nt) {
            const bf16x8 kb0 = *(const bf16x8*)&Ks[cur][nt * 16 + c][quad * 8];
            const bf16x8 kb1 = *(const bf16x8*)&Ks[cur][nt * 16 + c][32 + quad * 8];
            f32x4 sv = (f32x4){0.f, 0.f, 0.f, 0.f};
            sv = __builtin_amdgcn_mfma_f32_16x16x32_bf16(aq0, kb0, sv, 0, 0, 0);
            sv = __builtin_amdgcn_mfma_f32_16x16x32_bf16(aq1, kb1, sv, 0, 0, 0);
            const float rl = rls[cur][nt * 16 + c];
#pragma unroll
            for (int r = 0; r < 4; ++r)
                Ps[w][quad * 4 + r][nt * 16 + c] = f2bf(__expf(sv[r]) * rl);
        }
        // wave-private: same-wave DS ops are in-order, no block barrier
        const bf16x8 ap0 = *(const bf16x8*)&Ps[w][c][quad * 8];
        const bf16x8 ap1 = *(const bf16x8*)&Ps[w][c][32 + quad * 8];
#pragma unroll
        for (int dn = 0; dn < 4; ++dn) {
            const bf16x8 vb0 = *(const bf16x8*)&Vs[cur][dn * 16 + c][quad * 8];
            const bf16x8 vb1 = *(const bf16x8*)&Vs[cur][dn * 16 + c][32 + quad * 8];
            acc[dn] = __builtin_amdgcn_mfma_f32_16x16x32_bf16(ap0, vb0, acc[dn], 0, 0, 0);
            acc[dn] = __builtin_amdgcn_mfma_f32_16x16x32_bf16(ap1, vb1, acc[dn], 0, 0, 0);
        }

        if (jt2 < 7) {
            *(bf16x8*)&Ks[1 - cur][r0][cc]     = pk0;
            *(bf16x8*)&Ks[1 - cur][r0][cc + 8] = pk1;
            *(bf16x8*)&Vs[1 - cur][r0][cc]     = pv0;
            *(bf16x8*)&Vs[1 - cur][r0][cc + 8] = pv1;
            if (t < 64) rls[1 - cur][t] = nrl;
        }
        __syncthreads();
    }

    float* op = outp + (size_t)s * (Bn * Nn * DHn) + ((size_t)b * Nn + ibase) * DHn;
#pragma unroll
    for (int dn = 0; dn < 4; ++dn)
#pragma unroll
        for (int r = 0; r < 4; ++r)
            op[(w * 16 + quad * 4 + r) * DHn + dn * 16 + c] = acc[dn][r];
}

// ---------------------------------------------------------------------------
// Reduce the 4 partial buffers into out.
// ---------------------------------------------------------------------------
__global__ __launch_bounds__(256) void outreduce_kernel(
    const float* __restrict__ outp, float* __restrict__ out)
{
    const int id = blockIdx.x * 256 + threadIdx.x;   // 262144 float4
    const float4* p = (const float4*)outp;
    const float4 a = p[id];
    const float4 b = p[id + 262144];
    const float4 c = p[id + 2 * 262144];
    const float4 d = p[id + 3 * 262144];
    float4 r;
    r.x = a.x + b.x + c.x + d.x;
    r.y = a.y + b.y + c.y + d.y;
    r.z = a.z + b.z + c.z + d.z;
    r.w = a.w + b.w + c.w + d.w;
    ((float4*)out)[id] = r;
}

// ---------------------------------------------------------------------------
extern "C" void kernel_launch(void* const* d_in, const int* in_sizes, int n_in,
                              void* d_out, int out_size, void* d_ws, size_t ws_size,
                              hipStream_t stream)
{
    const float* x  = (const float*)d_in[0];
    const float* Wq = (const float*)d_in[1];
    const float* bq = (const float*)d_in[2];
    const float* Wk = (const float*)d_in[3];
    const float* bk = (const float*)d_in[4];
    const float* Wv = (const float*)d_in[5];
    const float* bv = (const float*)d_in[6];
    float* out = (float*)d_out;

    char* ws = (char*)d_ws;
    short* Qb    = (short*)(ws);                                   // 2 MB
    short* Kb    = (short*)(ws + (size_t)(1 << 21));               // 2 MB
    short* Vt    = (short*)(ws + (size_t)(2 << 21));               // 2 MB [b][d][j]
    short* Wtf   = (short*)(ws + (size_t)(3 << 21));               // 384 KB (frag-major)
    float* lpart = (float*)(ws + (size_t)(3 << 21) + (1 << 19));   // 256 KB (4 splits)
    float* outp  = (float*)(ws + (size_t)(7 << 20));               // 16 MB (4 partials)

    wt_kernel<<<dim3(192), dim3(128), 0, stream>>>(Wq, Wk, Wv, Wtf);
    qkv_kernel<<<dim3(512), dim3(256), 0, stream>>>(x, Wtf, bq, bk, bv, Qb, Kb, Vt);
    colsum_kernel<<<dim3(1024), dim3(256), 0, stream>>>(Qb, Kb, lpart);
    attnout_kernel<<<dim3(1024), dim3(256), 0, stream>>>(Qb, Kb, Vt, lpart, outp);
    outreduce_kernel<<<dim3(1024), dim3(256), 0, stream>>>(outp, out);
}

// Round 10
// 157.437 us; speedup vs baseline: 1.3632x; 1.0185x over previous
//
#include <hip/hip_runtime.h>
#include <math.h>

// Problem constants (HeadAttention_738734374917)
#define Bn  8
#define Nn  2048
#define Dn  1024
#define DHn 64
#define PAD  72  // LDS row pitch (shorts) for 64-wide tiles
#define PADP 72  // LDS row pitch for Ps — must hold 64 cols; 72 = 2-way banks (free)

typedef __attribute__((ext_vector_type(8))) short bf16x8;  // 8 bf16 = 4 VGPRs
typedef __attribute__((ext_vector_type(4))) float f32x4;

static __device__ inline short f2bf(float f) {
    unsigned u = __builtin_bit_cast(unsigned, f);
    u += 0x7FFFu + ((u >> 16) & 1u);     // round-to-nearest-even
    return (short)(u >> 16);
}
static __device__ inline bf16x8 pack8(float4 a, float4 b) {
    bf16x8 v;
    v[0] = f2bf(a.x); v[1] = f2bf(a.y); v[2] = f2bf(a.z); v[3] = f2bf(a.w);
    v[4] = f2bf(b.x); v[5] = f2bf(b.y); v[6] = f2bf(b.z); v[7] = f2bf(b.w);
    return v;
}

// ---------------------------------------------------------------------------
// Wt in B-FRAG-MAJOR order: Wtf[ntg 0..11][kt 0..15][half 0..1][lane 0..63][e 0..7]
// ---------------------------------------------------------------------------
__global__ __launch_bounds__(128) void wt_kernel(
    const float* __restrict__ Wq, const float* __restrict__ Wk,
    const float* __restrict__ Wv, short* __restrict__ Wtf)
{
    const int nt = blockIdx.x / 16, kt = blockIdx.x % 16;
    const int t = threadIdx.x;
    const int half = t >> 6, l = t & 63;
    const int c = l & 15, quad = l >> 4;
    const int mat = nt >> 2, cm = (nt & 3) * 16 + c;
    const float* Wm = (mat == 0) ? Wq : (mat == 1 ? Wk : Wv);
    short* o = &Wtf[((((size_t)nt * 16 + kt) * 2 + half) * 64 + l) * 8];
#pragma unroll
    for (int e = 0; e < 8; ++e) {
        const int k = kt * 64 + half * 32 + quad * 8 + e;
        o[e] = f2bf(Wm[(size_t)k * DHn + cm]);
    }
}

// ---------------------------------------------------------------------------
// K1: QKV projection (r8 structure, unchanged): M=32, grid 512, dbuf xs,
// one barrier/kt, frag-major Wtf B-loads.
// Outputs: Qb[i][d], Kb[j][d]*0.125, Vt[b][d][j] — all bf16.
// ---------------------------------------------------------------------------
__global__ __launch_bounds__(256) void qkv_kernel(
    const float* __restrict__ x, const short* __restrict__ Wtf,
    const float* __restrict__ bq, const float* __restrict__ bk,
    const float* __restrict__ bv,
    short* __restrict__ Qb, short* __restrict__ Kb, short* __restrict__ Vt)
{
    __shared__ __attribute__((aligned(16))) short xs[2][32][PAD];

    const int t = threadIdx.x;
    const int w = t >> 6, l = t & 63;
    const int c = l & 15, quad = l >> 4;
    const int ibase = blockIdx.x * 32;
    const int r0 = t >> 3, kc = t & 7;

    const float* xrow = &x[(size_t)(ibase + r0) * Dn + kc * 8];

    {
        const float4 a = ((const float4*)xrow)[0];
        const float4 b = ((const float4*)xrow)[1];
        *(bf16x8*)&xs[0][r0][kc * 8] = pack8(a, b);
    }

    f32x4 acc[2][3];
#pragma unroll
    for (int mt = 0; mt < 2; ++mt)
#pragma unroll
        for (int nt = 0; nt < 3; ++nt) acc[mt][nt] = (f32x4){0.f, 0.f, 0.f, 0.f};

    __syncthreads();

    for (int kt = 0; kt < 16; ++kt) {
        const int cur = kt & 1;
        float4 pa, pb;
        if (kt < 15) {
            pa = ((const float4*)(xrow + (kt + 1) * 64))[0];
            pb = ((const float4*)(xrow + (kt + 1) * 64))[1];
        }
#pragma unroll
        for (int h = 0; h < 2; ++h) {
            const bf16x8 af0 = *(const bf16x8*)&xs[cur][c][h * 32 + quad * 8];
            const bf16x8 af1 = *(const bf16x8*)&xs[cur][16 + c][h * 32 + quad * 8];
#pragma unroll
            for (int nt = 0; nt < 3; ++nt) {
                const int ntg = w * 3 + nt;
                const bf16x8 bf = *(const bf16x8*)&Wtf[((((size_t)ntg * 16 + kt) * 2 + h) * 64 + l) * 8];
                acc[0][nt] = __builtin_amdgcn_mfma_f32_16x16x32_bf16(af0, bf, acc[0][nt], 0, 0, 0);
                acc[1][nt] = __builtin_amdgcn_mfma_f32_16x16x32_bf16(af1, bf, acc[1][nt], 0, 0, 0);
            }
        }
        if (kt < 15) *(bf16x8*)&xs[1 - cur][r0][kc * 8] = pack8(pa, pb);
        __syncthreads();
    }

#pragma unroll
    for (int nt = 0; nt < 3; ++nt) {
        const int col = w * 48 + nt * 16 + c;
        const int mat = col >> 6, cm = col & 63;
        const float bias = (mat == 0 ? bq : (mat == 1 ? bk : bv))[cm];
#pragma unroll
        for (int mt = 0; mt < 2; ++mt) {
            if (mat == 2) {
                const int row = ibase + mt * 16 + quad * 4;
                const int b = row >> 11, i = row & (Nn - 1);
                ushort4 o;
                o.x = (unsigned short)f2bf(acc[mt][nt][0] + bias);
                o.y = (unsigned short)f2bf(acc[mt][nt][1] + bias);
                o.z = (unsigned short)f2bf(acc[mt][nt][2] + bias);
                o.w = (unsigned short)f2bf(acc[mt][nt][3] + bias);
                *(ushort4*)&Vt[((size_t)b * DHn + cm) * Nn + i] = o;
            } else {
                const float s = (mat == 1) ? 0.125f : 1.0f;
                short* Out = (mat == 0) ? Qb : Kb;
#pragma unroll
                for (int r = 0; r < 4; ++r)
                    Out[(size_t)(ibase + mt * 16 + quad * 4 + r) * DHn + cm] =
                        f2bf((acc[mt][nt][r] + bias) * s);
            }
        }
    }
}

// ---------------------------------------------------------------------------
// K2: l_part[s][b][j] = sum_{i in split s} exp(Q_i . K'_j).
// Grid (b, j-tile 64, i-split 4) = 1024.  K-frags register-resident; wave-
// private Q staging, TWO 16-row chunks per pipeline iter (ILP on exp chains).
// ---------------------------------------------------------------------------
__global__ __launch_bounds__(256) void colsum_kernel(
    const short* __restrict__ Qb, const short* __restrict__ Kb,
    float* __restrict__ lpart)
{
    __shared__ __attribute__((aligned(16))) short Qw[4][2][32][PAD];
    __shared__ float red[16][64];

    const int t = threadIdx.x;
    const int w = t >> 6, l = t & 63;
    const int c = l & 15, quad = l >> 4;
    const int bid = blockIdx.x;
    const int b = bid >> 7, rem = bid & 127, jt = rem >> 2, s = rem & 3;
    const int jbase = jt * 64;
    const int srow = l >> 1, scoff = (l & 1) * 32;   // staging: 32 rows, half-row/lane

    bf16x8 kb[4][2];
#pragma unroll
    for (int nt = 0; nt < 4; ++nt)
#pragma unroll
        for (int kk = 0; kk < 2; ++kk)
            kb[nt][kk] = *(const bf16x8*)&Kb[((size_t)b * Nn + jbase + nt * 16 + c) * DHn
                                             + kk * 32 + quad * 8];

    // wave w owns contiguous 128 i: s*512 + w*128, 4 iters of 32 rows
    const short* qbase = &Qb[((size_t)b * Nn + s * 512 + w * 128 + srow) * DHn + scoff];

    // stage it2=0 into buf 0 (wave-private, 4 b128/lane)
#pragma unroll
    for (int k = 0; k < 4; ++k)
        *(bf16x8*)&Qw[w][0][srow][scoff + k * 8] = *(const bf16x8*)(qbase + k * 8);

    float lsum[4] = {0.f, 0.f, 0.f, 0.f};

    for (int it2 = 0; it2 < 4; ++it2) {
        const int cur = it2 & 1;
        bf16x8 p[4];
        if (it2 < 3) {
            const short* pq = qbase + (size_t)(it2 + 1) * 32 * DHn;
#pragma unroll
            for (int k = 0; k < 4; ++k) p[k] = *(const bf16x8*)(pq + k * 8);
        }
        // two independent 16-row chunks
#pragma unroll
        for (int cc2 = 0; cc2 < 2; ++cc2) {
            const bf16x8 aq0 = *(const bf16x8*)&Qw[w][cur][cc2 * 16 + c][quad * 8];
            const bf16x8 aq1 = *(const bf16x8*)&Qw[w][cur][cc2 * 16 + c][32 + quad * 8];
#pragma unroll
            for (int nt = 0; nt < 4; ++nt) {
                f32x4 sv = (f32x4){0.f, 0.f, 0.f, 0.f};
                sv = __builtin_amdgcn_mfma_f32_16x16x32_bf16(aq0, kb[nt][0], sv, 0, 0, 0);
                sv = __builtin_amdgcn_mfma_f32_16x16x32_bf16(aq1, kb[nt][1], sv, 0, 0, 0);
                lsum[nt] += __expf(sv[0]) + __expf(sv[1]) + __expf(sv[2]) + __expf(sv[3]);
            }
        }
        if (it2 < 3) {
#pragma unroll
            for (int k = 0; k < 4; ++k)
                *(bf16x8*)&Qw[w][1 - cur][srow][scoff + k * 8] = p[k];
        }
        // no barrier: Qw[w] is wave-private, DS ops in-order per wave
    }

#pragma unroll
    for (int nt = 0; nt < 4; ++nt) red[w * 4 + quad][nt * 16 + c] = lsum[nt];
    __syncthreads();
    if (t < 64) {
        float sum = 0.f;
#pragma unroll
        for (int r = 0; r < 16; ++r) sum += red[r][t];
        lpart[((size_t)s * Bn + b) * Nn + jbase + t] = sum;   // plain store
    }
}

// ---------------------------------------------------------------------------
// K3: outp[s][i,:] = sum_{j in s} (exp(Q_i.K'_j)/l_j) V[j,:].
// Grid = (b, i-tile 128, j-split 8) = 1024.  Each wave: 32 i (2 subtiles)
// sharing staged K/V tile AND kb/vb frag reads.  Dbuf staging, 1 barrier/tile.
// ---------------------------------------------------------------------------
__global__ __launch_bounds__(256) void attnout_kernel(
    const short* __restrict__ Qb, const short* __restrict__ Kb,
    const short* __restrict__ Vt, const float* __restrict__ lpart,
    float* __restrict__ outp)
{
    __shared__ __attribute__((aligned(16))) short Ks[2][64][PAD];
    __shared__ __attribute__((aligned(16))) short Vs[2][64][PAD];
    __shared__ __attribute__((aligned(16))) short Ps[4][32][PADP];  // wave-private
    __shared__ float rls[2][64];

    const int t = threadIdx.x;
    const int w = t >> 6, lane = t & 63;
    const int c = lane & 15, quad = lane >> 4;
    const int bid = blockIdx.x;
    const int b = bid >> 7, rem = bid & 127, it = rem >> 3, s = rem & 7;
    const int ibase = it * 128;
    const int r0 = t >> 2, cc = (t & 3) * 16;

    // Q A-frags: 2 subtiles x 2 halves (wave's 32 i-rows)
    bf16x8 aq[2][2];
#pragma unroll
    for (int sub = 0; sub < 2; ++sub) {
        const size_t qrow = (size_t)b * Nn + ibase + w * 32 + sub * 16 + c;
        aq[sub][0] = *(const bf16x8*)&Qb[qrow * DHn + quad * 8];
        aq[sub][1] = *(const bf16x8*)&Qb[qrow * DHn + 32 + quad * 8];
    }

    const short* kbase = &Kb[((size_t)b * Nn + s * 256 + r0) * DHn + cc];
    const short* vbase = &Vt[((size_t)b * DHn + r0) * Nn + s * 256 + cc];

    // stage tile 0 + rls[0]
    *(bf16x8*)&Ks[0][r0][cc]     = *(const bf16x8*)kbase;
    *(bf16x8*)&Ks[0][r0][cc + 8] = *(const bf16x8*)(kbase + 8);
    *(bf16x8*)&Vs[0][r0][cc]     = *(const bf16x8*)vbase;
    *(bf16x8*)&Vs[0][r0][cc + 8] = *(const bf16x8*)(vbase + 8);
    if (t < 64) {
        const size_t lj = (size_t)b * Nn + s * 256 + t;
        rls[0][t] = 1.0f / (lpart[lj] + lpart[(size_t)Bn * Nn + lj]
                          + lpart[2 * (size_t)Bn * Nn + lj] + lpart[3 * (size_t)Bn * Nn + lj]);
    }

    f32x4 acc[2][4];
#pragma unroll
    for (int sub = 0; sub < 2; ++sub)
#pragma unroll
        for (int dn = 0; dn < 4; ++dn) acc[sub][dn] = (f32x4){0.f, 0.f, 0.f, 0.f};
    __syncthreads();

    for (int jt2 = 0; jt2 < 4; ++jt2) {
        const int cur = jt2 & 1;
        bf16x8 pk0, pk1, pv0, pv1; float nrl;
        if (jt2 < 3) {
            const short* pk = kbase + (size_t)(jt2 + 1) * 64 * DHn;
            pk0 = *(const bf16x8*)pk; pk1 = *(const bf16x8*)(pk + 8);
            const short* pv = vbase + (jt2 + 1) * 64;
            pv0 = *(const bf16x8*)pv; pv1 = *(const bf16x8*)(pv + 8);
            if (t < 64) {
                const size_t lj = (size_t)b * Nn + s * 256 + (jt2 + 1) * 64 + t;
                nrl = 1.0f / (lpart[lj] + lpart[(size_t)Bn * Nn + lj]
                            + lpart[2 * (size_t)Bn * Nn + lj] + lpart[3 * (size_t)Bn * Nn + lj]);
            }
        }

        // S for both subtiles, sharing kb frag reads
#pragma unroll
        for (int nt = 0; nt < 4; ++nt) {
            const bf16x8 kb0 = *(const bf16x8*)&Ks[cur][nt * 16 + c][quad * 8];
            const bf16x8 kb1 = *(const bf16x8*)&Ks[cur][nt * 16 + c][32 + quad * 8];
            const float rl = rls[cur][nt * 16 + c];
#pragma unroll
            for (int sub = 0; sub < 2; ++sub) {
                f32x4 sv = (f32x4){0.f, 0.f, 0.f, 0.f};
                sv = __builtin_amdgcn_mfma_f32_16x16x32_bf16(aq[sub][0], kb0, sv, 0, 0, 0);
                sv = __builtin_amdgcn_mfma_f32_16x16x32_bf16(aq[sub][1], kb1, sv, 0, 0, 0);
#pragma unroll
                for (int r = 0; r < 4; ++r)
                    Ps[w][sub * 16 + quad * 4 + r][nt * 16 + c] = f2bf(__expf(sv[r]) * rl);
            }
        }
        // wave-private Ps: same-wave DS in-order, no block barrier
        bf16x8 ap[2][2];
#pragma unroll
        for (int sub = 0; sub < 2; ++sub) {
            ap[sub][0] = *(const bf16x8*)&Ps[w][sub * 16 + c][quad * 8];
            ap[sub][1] = *(const bf16x8*)&Ps[w][sub * 16 + c][32 + quad * 8];
        }
#pragma unroll
        for (int dn = 0; dn < 4; ++dn) {
            const bf16x8 vb0 = *(const bf16x8*)&Vs[cur][dn * 16 + c][quad * 8];
            const bf16x8 vb1 = *(const bf16x8*)&Vs[cur][dn * 16 + c][32 + quad * 8];
#pragma unroll
            for (int sub = 0; sub < 2; ++sub) {
                acc[sub][dn] = __builtin_amdgcn_mfma_f32_16x16x32_bf16(ap[sub][0], vb0, acc[sub][dn], 0, 0, 0);
                acc[sub][dn] = __builtin_amdgcn_mfma_f32_16x16x32_bf16(ap[sub][1], vb1, acc[sub][dn], 0, 0, 0);
            }
        }

        if (jt2 < 3) {
            *(bf16x8*)&Ks[1 - cur][r0][cc]     = pk0;
            *(bf16x8*)&Ks[1 - cur][r0][cc + 8] = pk1;
            *(bf16x8*)&Vs[1 - cur][r0][cc]     = pv0;
            *(bf16x8*)&Vs[1 - cur][r0][cc + 8] = pv1;
            if (t < 64) rls[1 - cur][t] = nrl;
        }
        __syncthreads();
    }

    float* op = outp + (size_t)s * (Bn * Nn * DHn) + ((size_t)b * Nn + ibase) * DHn;
#pragma unroll
    for (int sub = 0; sub < 2; ++sub)
#pragma unroll
        for (int dn = 0; dn < 4; ++dn)
#pragma unroll
            for (int r = 0; r < 4; ++r)
                op[(w * 32 + sub * 16 + quad * 4 + r) * DHn + dn * 16 + c] = acc[sub][dn][r];
}

// ---------------------------------------------------------------------------
// Reduce the 8 partial buffers into out.
// ---------------------------------------------------------------------------
__global__ __launch_bounds__(256) void outreduce_kernel(
    const float* __restrict__ outp, float* __restrict__ out)
{
    const int id = blockIdx.x * 256 + threadIdx.x;   // 262144 float4
    const float4* p = (const float4*)outp;
    float4 r = p[id];
#pragma unroll
    for (int k = 1; k < 8; ++k) {
        const float4 a = p[id + (size_t)k * 262144];
        r.x += a.x; r.y += a.y; r.z += a.z; r.w += a.w;
    }
    ((float4*)out)[id] = r;
}

// ---------------------------------------------------------------------------
extern "C" void kernel_launch(void* const* d_in, const int* in_sizes, int n_in,
                              void* d_out, int out_size, void* d_ws, size_t ws_size,
                              hipStream_t stream)
{
    const float* x  = (const float*)d_in[0];
    const float* Wq = (const float*)d_in[1];
    const float* bq = (const float*)d_in[2];
    const float* Wk = (const float*)d_in[3];
    const float* bk = (const float*)d_in[4];
    const float* Wv = (const float*)d_in[5];
    const float* bv = (const float*)d_in[6];
    float* out = (float*)d_out;

    char* ws = (char*)d_ws;
    short* Qb    = (short*)(ws);                                   // 2 MB
    short* Kb    = (short*)(ws + (size_t)(1 << 21));               // 2 MB
    short* Vt    = (short*)(ws + (size_t)(2 << 21));               // 2 MB [b][d][j]
    short* Wtf   = (short*)(ws + (size_t)(3 << 21));               // 384 KB (frag-major)
    float* lpart = (float*)(ws + (size_t)(3 << 21) + (1 << 19));   // 256 KB (4 splits)
    float* outp  = (float*)(ws + (size_t)(7 << 20));               // 32 MB (8 partials)

    wt_kernel<<<dim3(192), dim3(128), 0, stream>>>(Wq, Wk, Wv, Wtf);
    qkv_kernel<<<dim3(512), dim3(256), 0, stream>>>(x, Wtf, bq, bk, bv, Qb, Kb, Vt);
    colsum_kernel<<<dim3(1024), dim3(256), 0, stream>>>(Qb, Kb, lpart);
    attnout_kernel<<<dim3(1024), dim3(256), 0, stream>>>(Qb, Kb, Vt, lpart, outp);
    outreduce_kernel<<<dim3(1024), dim3(256), 0, stream>>>(outp, out);
}